// Round 3
// baseline (150.049 us; speedup 1.0000x reference)
//
#include <hip/hip_runtime.h>
#include <hip/hip_bf16.h>
#include <cstdint>

typedef __attribute__((ext_vector_type(8))) short short8;
typedef __attribute__((ext_vector_type(8))) unsigned short ushort8;
typedef __attribute__((ext_vector_type(4))) float f32x4;

#define B_TRIALS 256
#define F_BINS   100
#define N_UNITS  512
#define P_CH     512
#define G_SESS   10
#define H_DIM    1024  // 2N
#define TOT_ROWS (B_TRIALS * F_BINS)  // 25600
#define NT_MAX   110                  // max 256-row tiles over 10 session groups

// f32 -> bf16 round-to-nearest-even (finite inputs)
__device__ __forceinline__ unsigned short f2bf(float f) {
  unsigned int u = __builtin_bit_cast(unsigned int, f);
  u += 0x7fffu + ((u >> 16) & 1u);
  return (unsigned short)(u >> 16);
}

// async global->LDS, 16B per lane; lds dest must be wave-uniform base (+lane*16 by HW)
__device__ __forceinline__ void gload16(const void* gsrc, void* ldst) {
  __builtin_amdgcn_global_load_lds(
      (const __attribute__((address_space(1))) unsigned int*)gsrc,
      (__attribute__((address_space(3))) unsigned int*)ldst, 16, 0, 0);
}

// ---------------- planner: stable counting sort of trials by eid ----------------
// rowmap[compact_row] = trial*100 + frow ; tile_meta[t] = {g, row0, valid_rows}
__global__ void planner(const int* __restrict__ eid, int* __restrict__ rowmap,
                        int* __restrict__ tile_meta) {
  __shared__ int e[B_TRIALS], cnt[G_SESS], off[G_SESS], groff[G_SESS + 1], perm[B_TRIALS];
  int t = threadIdx.x;
  e[t] = eid[t];
  if (t < G_SESS) cnt[t] = 0;
  __syncthreads();
  atomicAdd(&cnt[e[t]], 1);
  __syncthreads();
  if (t == 0) {
    int s = 0, r = 0;
    for (int g = 0; g < G_SESS; g++) {
      off[g] = s; s += cnt[g];
      groff[g] = r; r += cnt[g] * F_BINS;
    }
    groff[G_SESS] = r;  // 25600
  }
  __syncthreads();
  // stable rank within group
  int g = e[t], rank = 0;
  for (int j = 0; j < t; j++) rank += (e[j] == g);
  perm[off[g] + rank] = t;
  __syncthreads();
  for (int i = t; i < TOT_ROWS; i += 256) {
    int gg = 0;
    while (gg + 1 < G_SESS && i >= groff[gg + 1]) gg++;
    int loc = i - groff[gg];
    rowmap[i] = perm[off[gg] + loc / F_BINS] * F_BINS + loc % F_BINS;
  }
  if (t == 0) {
    int ti = 0;
    for (int g2 = 0; g2 < G_SESS; g2++) {
      int rows = cnt[g2] * F_BINS;
      int base = groff[g2];
      for (int r0 = 0; r0 < rows; r0 += 256) {
        tile_meta[ti * 3 + 0] = g2;
        tile_meta[ti * 3 + 1] = base + r0;
        tile_meta[ti * 3 + 2] = (rows - r0 < 256) ? (rows - r0) : 256;
        ti++;
      }
    }
    for (; ti < NT_MAX; ti++) {
      tile_meta[ti * 3 + 0] = -1; tile_meta[ti * 3 + 1] = 0; tile_meta[ti * 3 + 2] = 0;
    }
  }
}

// ---------------- one-time casts ----------------
__global__ void cast_x(const float* __restrict__ src,
                       unsigned short* __restrict__ dst, int n8) {
  int i = blockIdx.x * blockDim.x + threadIdx.x;
  int stride = gridDim.x * blockDim.x;
  for (; i < n8; i += stride) {
    float4 v0 = ((const float4*)src)[(size_t)i * 2];
    float4 v1 = ((const float4*)src)[(size_t)i * 2 + 1];
    ushort8 w;
    w[0] = f2bf(v0.x); w[1] = f2bf(v0.y); w[2] = f2bf(v0.z); w[3] = f2bf(v0.w);
    w[4] = f2bf(v1.x); w[5] = f2bf(v1.y); w[6] = f2bf(v1.z); w[7] = f2bf(v1.w);
    ((ushort8*)dst)[i] = w;
  }
}

// src: [g][K][N] f32 -> dst: [g][N][K] bf16
__global__ void cast_transpose(const float* __restrict__ src,
                               unsigned short* __restrict__ dst,
                               int K, int N) {
  __shared__ float tile[32][33];
  int g = blockIdx.z;
  int n0 = blockIdx.x * 32, k0 = blockIdx.y * 32;
  const float* s = src + (size_t)g * K * N;
  unsigned short* d = dst + (size_t)g * N * K;
  int t = threadIdx.x;
  int r = t >> 3, c = (t & 7) * 4;
  float4 v = *(const float4*)(s + (size_t)(k0 + r) * N + n0 + c);
  tile[r][c + 0] = v.x; tile[r][c + 1] = v.y;
  tile[r][c + 2] = v.z; tile[r][c + 3] = v.w;
  __syncthreads();
  ushort4 o;
  o.x = f2bf(tile[c + 0][r]);
  o.y = f2bf(tile[c + 1][r]);
  o.z = f2bf(tile[c + 2][r]);
  o.w = f2bf(tile[c + 3][r]);
  *(ushort4*)(d + (size_t)(n0 + r) * K + k0 + c) = o;
}

// ---------------- grouped 256x256 GEMM, BK=32, 4-buf 3-deep counted-vmcnt ----------------
// IS2=false: A = xb gathered via rowmap (LDA=512), epilogue softsign -> h bf16 (compact rows)
// IS2=true : A = h linear (LDA=1024), epilogue +b2 -> out f32 scattered via rowmap

#define STAGE(kt) do {                                                      \
    int _b = (kt) & 3; int _k0 = (kt) * 32;                                 \
    gload16(b0p + _k0, &Bb[_b][(size_t)(tid & 448) * 8]);                   \
    gload16(b1p + _k0, &Bb[_b][(size_t)(512 + (tid & 448)) * 8]);           \
    gload16(a0p + _k0, &Ab[_b][(size_t)(tid & 448) * 8]);                   \
    gload16(a1p + _k0, &Ab[_b][(size_t)(512 + (tid & 448)) * 8]);           \
  } while (0)

#define KSTEP(kt, VM) do {                                                  \
    asm volatile("s_waitcnt vmcnt(" #VM ")" ::: "memory");                  \
    __builtin_amdgcn_s_barrier();                                           \
    asm volatile("" ::: "memory");                                          \
    const unsigned short* Ap = &Ab[(kt) & 3][0];                            \
    const unsigned short* Bp = &Bb[(kt) & 3][0];                            \
    short8 av[8], bv[4];                                                    \
    _Pragma("unroll")                                                       \
    for (int m = 0; m < 8; m++) {                                           \
      int rw = wm * 128 + m * 16 + lr;                                      \
      av[m] = *(const short8*)&Ap[rw * 32 + sl8];                           \
    }                                                                       \
    _Pragma("unroll")                                                       \
    for (int n = 0; n < 4; n++) {                                           \
      int cl = wn * 64 + n * 16 + lr;                                       \
      bv[n] = *(const short8*)&Bp[cl * 32 + sl8];                           \
    }                                                                       \
    __builtin_amdgcn_s_setprio(1);                                          \
    _Pragma("unroll")                                                       \
    for (int n = 0; n < 4; n++)                                             \
      _Pragma("unroll")                                                     \
      for (int m = 0; m < 8; m++)                                           \
        acc[m][n] = __builtin_amdgcn_mfma_f32_16x16x32_bf16(av[m], bv[n], acc[m][n], 0, 0, 0); \
    __builtin_amdgcn_s_setprio(0);                                          \
    asm volatile("" ::: "memory");                                          \
    __builtin_amdgcn_s_barrier();                                           \
  } while (0)

template<int KTOT, int NOUT, bool IS2>
__global__ __launch_bounds__(512, 2) void gemm_grouped(
    const unsigned short* __restrict__ Asrc,
    const unsigned short* __restrict__ Wt,
    const float* __restrict__ bias,
    const int* __restrict__ rowmap,
    const int* __restrict__ tile_meta,
    unsigned short* __restrict__ hout,
    float* __restrict__ out) {
  __shared__ __align__(16) unsigned short Ab[4][256 * 32];  // 64 KiB
  __shared__ __align__(16) unsigned short Bb[4][256 * 32];  // 64 KiB

  const int mt = blockIdx.x;
  const int g = tile_meta[mt * 3 + 0];
  if (g < 0) return;
  const int row0 = tile_meta[mt * 3 + 1];
  const int valid = tile_meta[mt * 3 + 2];
  const int ncol0 = blockIdx.y * 256;

  const int tid = threadIdx.x;
  const int lane = tid & 63;
  const int w = tid >> 6;
  const int wm = w >> 2, wn = w & 3;          // 2 x 4 wave grid
  const int lr = lane & 15, lq = lane >> 4;
  const int sl8 = ((lq ^ ((lr >> 1) & 3)) * 8);  // swizzled 16B slot (in ushort elems)

  // staging sources: 2 B-chunks + 2 A-chunks per thread, constant layout over K
  const unsigned short* Wg = Wt + (size_t)g * NOUT * KTOT + (size_t)ncol0 * KTOT;
  const unsigned short *b0p, *b1p, *a0p, *a1p;
  {
    int idx0 = tid, idx1 = 512 + tid;
    int c0 = idx0 >> 2, q0 = idx0 & 3, ks0 = q0 ^ ((c0 >> 1) & 3);
    int c1 = idx1 >> 2, q1 = idx1 & 3, ks1 = q1 ^ ((c1 >> 1) & 3);
    b0p = Wg + (size_t)c0 * KTOT + ks0 * 8;
    b1p = Wg + (size_t)c1 * KTOT + ks1 * 8;
    int rr0 = row0 + c0; if (rr0 > TOT_ROWS - 1) rr0 = TOT_ROWS - 1;
    int rr1 = row0 + c1; if (rr1 > TOT_ROWS - 1) rr1 = TOT_ROWS - 1;
    int sr0 = IS2 ? rr0 : rowmap[rr0];
    int sr1 = IS2 ? rr1 : rowmap[rr1];
    a0p = Asrc + (size_t)sr0 * KTOT + ks0 * 8;
    a1p = Asrc + (size_t)sr1 * KTOT + ks1 * 8;
  }

  f32x4 acc[8][4];
#pragma unroll
  for (int m = 0; m < 8; m++)
#pragma unroll
    for (int n = 0; n < 4; n++) acc[m][n] = (f32x4){0.f, 0.f, 0.f, 0.f};

  constexpr int NK = KTOT / 32;
  STAGE(0); STAGE(1); STAGE(2);
#pragma unroll 4
  for (int kt = 0; kt < NK - 3; kt++) {
    STAGE(kt + 3);
    KSTEP(kt, 12);
  }
  KSTEP(NK - 3, 8);
  KSTEP(NK - 2, 4);
  KSTEP(NK - 1, 0);

  // epilogue
  float bv4[4];
#pragma unroll
  for (int n = 0; n < 4; n++)
    bv4[n] = bias[(size_t)g * NOUT + ncol0 + wn * 64 + n * 16 + lr];

  if (!IS2) {
#pragma unroll
    for (int m = 0; m < 8; m++)
#pragma unroll
      for (int r4 = 0; r4 < 4; r4++) {
        int lrow = wm * 128 + m * 16 + lq * 4 + r4;
        if (lrow < valid) {
          size_t base = (size_t)(row0 + lrow) * H_DIM + ncol0 + wn * 64 + lr;
#pragma unroll
          for (int n = 0; n < 4; n++) {
            float v = acc[m][n][r4] + bv4[n];
            v = v / (1.0f + fabsf(v));
            hout[base + n * 16] = f2bf(v);
          }
        }
      }
  } else {
#pragma unroll
    for (int m = 0; m < 8; m++)
#pragma unroll
      for (int r4 = 0; r4 < 4; r4++) {
        int lrow = wm * 128 + m * 16 + lq * 4 + r4;
        if (lrow < valid) {
          int orow = rowmap[row0 + lrow];
          size_t base = (size_t)orow * P_CH + ncol0 + wn * 64 + lr;
#pragma unroll
          for (int n = 0; n < 4; n++)
            out[base + n * 16] = acc[m][n][r4] + bv4[n];
        }
      }
  }
}

extern "C" void kernel_launch(void* const* d_in, const int* in_sizes, int n_in,
                              void* d_out, int out_size, void* d_ws, size_t ws_size,
                              hipStream_t stream) {
  const float* x  = (const float*)d_in[0];
  const int* eid  = (const int*)d_in[1];
  const float* W1 = (const float*)d_in[2];
  const float* b1 = (const float*)d_in[3];
  const float* W2 = (const float*)d_in[4];
  const float* b2 = (const float*)d_in[5];
  float* out = (float*)d_out;

  // ws layout (73,504,040 B):
  unsigned short* W1t = (unsigned short*)d_ws;                       // [10][1024][512] bf16
  unsigned short* W2t = W1t + (size_t)G_SESS * H_DIM * N_UNITS;      // [10][512][1024] bf16
  unsigned short* h   = W2t + (size_t)G_SESS * P_CH * H_DIM;         // [25600][1024] bf16 (compact grouped rows)
  int* rowmap    = (int*)(h + (size_t)TOT_ROWS * H_DIM);             // [25600]
  int* tile_meta = rowmap + TOT_ROWS;                                // [110][3]
  // xb (26.2MB bf16) in d_out (52.4MB): dead before gemm2 writes real output
  unsigned short* xb = (unsigned short*)d_out;                       // canonical [256][100][512] bf16

  planner<<<1, 256, 0, stream>>>(eid, rowmap, tile_meta);
  cast_x<<<2048, 256, 0, stream>>>(x, xb, B_TRIALS * F_BINS * N_UNITS / 8);
  cast_transpose<<<dim3(H_DIM / 32, N_UNITS / 32, G_SESS), 256, 0, stream>>>(W1, W1t, N_UNITS, H_DIM);
  cast_transpose<<<dim3(P_CH / 32, H_DIM / 32, G_SESS), 256, 0, stream>>>(W2, W2t, H_DIM, P_CH);
  gemm_grouped<N_UNITS, H_DIM, false><<<dim3(NT_MAX, 4), 512, 0, stream>>>(
      xb, W1t, b1, rowmap, tile_meta, h, out);
  gemm_grouped<H_DIM, P_CH, true><<<dim3(NT_MAX, 2), 512, 0, stream>>>(
      h, W2t, b2, rowmap, tile_meta, h, out);
}